// Round 2
// 354.020 us; speedup vs baseline: 1.0939x; 1.0939x over previous
//
#include <hip/hip_runtime.h>
#include <stdint.h>

// ---- types ----
typedef __attribute__((ext_vector_type(4))) float f32x4;
typedef __attribute__((ext_vector_type(16))) float f32x16;
typedef __attribute__((ext_vector_type(8))) short s16x8;
typedef __attribute__((ext_vector_type(4))) short s16x4;
typedef __attribute__((ext_vector_type(4))) unsigned int u32x4;
typedef __attribute__((ext_vector_type(8))) _Float16 f16x8;
typedef __attribute__((ext_vector_type(4))) _Float16 f16x4;
typedef __attribute__((ext_vector_type(2))) _Float16 f16x2;

#define MFMA16(a, b, c) __builtin_amdgcn_mfma_f32_16x16x32_bf16((a), (b), (c), 0, 0, 0)
#define MFMA32H(a, b, c) __builtin_amdgcn_mfma_f32_32x32x16_f16((a), (b), (c), 0, 0, 0)

// B=2, T=8192, D=256; rows = B*T = 16384 flat.

__device__ __forceinline__ unsigned short f2bf(float f) {
  unsigned int u = __float_as_uint(f);
  u += 0x7FFFu + ((u >> 16) & 1u);  // RNE
  return (unsigned short)(u >> 16);
}
__device__ __forceinline__ float bf2f(unsigned short h) {
  return __uint_as_float(((unsigned int)h) << 16);
}
__device__ __forceinline__ unsigned pk16(float a, float b) {
  f16x2 p;
  p[0] = (_Float16)a;  // RNE, same numerics as the old per-element stores
  p[1] = (_Float16)b;
  return __builtin_bit_cast(unsigned, p);
}

// ---------------- kernel 1: weight transpose + hi/lo split (bf16) -----------
__global__ void wtrans_kernel(const float* __restrict__ Wq,
                              const float* __restrict__ Wk,
                              const float* __restrict__ Wv,
                              short* __restrict__ wt) {
  int idx = blockIdx.x * 256 + threadIdx.x;   // 768 blocks * 256
  int w = idx >> 16;
  int rc = idx & 65535;
  int d = rc >> 8;
  int n = rc & 255;
  const float* Ws = (w == 0) ? Wq : ((w == 1) ? Wk : Wv);
  float v = Ws[rc];
  unsigned short hi = f2bf(v);
  unsigned short lo = f2bf(v - bf2f(hi));
  short* th = wt + w * 131072;
  th[n * 256 + d] = (short)hi;
  th[65536 + n * 256 + d] = (short)lo;
}

// ---------------- kernel 2: QKV projection (3-term bf16 MFMA) ----------------
// Outputs fp16: Qf/Kf [16384][256], Vt [2][256][8192].
__global__ __launch_bounds__(256, 2)
void qkv_kernel(const float* __restrict__ x,
                const float* __restrict__ bq,
                const float* __restrict__ bk,
                const float* __restrict__ bv,
                const short* __restrict__ wt,
                short* __restrict__ Qf, short* __restrict__ Kf,
                short* __restrict__ Vt) {
  __shared__ short X[16896];
  int tid = threadIdx.x;
  int r0 = blockIdx.x * 32;
  int bidx = r0 >> 13;
  int tl0 = r0 & 8191;
#pragma unroll
  for (int i = 0; i < 8; i++) {
    int E = i * 1024 + tid * 4;
    int r = E >> 8, col = E & 255;
    f32x4 v = *(const f32x4*)(x + (size_t)(r0 + r) * 256 + col);
    s16x4 h, lo;
#pragma unroll
    for (int j = 0; j < 4; j++) {
      unsigned short hh = f2bf(v[j]);
      h[j] = (short)hh;
      lo[j] = (short)f2bf(v[j] - bf2f(hh));
    }
    *(s16x4*)&X[r * 264 + col] = h;
    *(s16x4*)&X[8448 + r * 264 + col] = lo;
  }
  __syncthreads();

  int lane = tid & 63, wv = tid >> 6;
  int quad = lane >> 4, lq = lane & 15;

  {
    int strip = wv & 1;
    const short* WhT = wt + ((wv < 2) ? 0 : 131072);
    const short* WlT = WhT + 65536;
    f32x4 acc[16];
#pragma unroll
    for (int nt = 0; nt < 16; nt++) acc[nt] = (f32x4){0.f, 0.f, 0.f, 0.f};
    int arow = (strip * 16 + lq) * 264 + quad * 8;
#pragma unroll
    for (int c = 0; c < 8; c++) {
      s16x8 xh = *(const s16x8*)&X[arow + c * 32];
      s16x8 xl = *(const s16x8*)&X[8448 + arow + c * 32];
#pragma unroll
      for (int nt = 0; nt < 16; nt++) {
        int boff = (nt * 16 + lq) * 256 + c * 32 + quad * 8;
        s16x8 wh = *(const s16x8*)(WhT + boff);
        s16x8 wl = *(const s16x8*)(WlT + boff);
        acc[nt] = MFMA16(xh, wh, acc[nt]);
        acc[nt] = MFMA16(xl, wh, acc[nt]);
        acc[nt] = MFMA16(xh, wl, acc[nt]);
      }
    }
    const float* bias = (wv < 2) ? bq : bk;
    _Float16* Of = (_Float16*)((wv < 2) ? Qf : Kf);
#pragma unroll
    for (int nt = 0; nt < 16; nt++) {
      int col = nt * 16 + lq;
      float bb = bias[col];
#pragma unroll
      for (int r = 0; r < 4; r++) {
        int row = r0 + strip * 16 + quad * 4 + r;
        Of[row * 256 + col] = (_Float16)(acc[nt][r] + bb);
      }
    }
  }
  {
    const short* WhT = wt + 262144;
    const short* WlT = wt + 327680;
    f32x4 acc[4][2];
#pragma unroll
    for (int mt = 0; mt < 4; mt++)
#pragma unroll
      for (int nt = 0; nt < 2; nt++) acc[mt][nt] = (f32x4){0.f, 0.f, 0.f, 0.f};
#pragma unroll
    for (int c = 0; c < 8; c++) {
      int co = c * 32 + quad * 8;
      s16x8 xh0 = *(const s16x8*)&X[lq * 264 + co];
      s16x8 xl0 = *(const s16x8*)&X[8448 + lq * 264 + co];
      s16x8 xh1 = *(const s16x8*)&X[(16 + lq) * 264 + co];
      s16x8 xl1 = *(const s16x8*)&X[8448 + (16 + lq) * 264 + co];
#pragma unroll
      for (int mt = 0; mt < 4; mt++) {
        int aoff = (wv * 64 + mt * 16 + lq) * 256 + co;
        s16x8 wh = *(const s16x8*)(WhT + aoff);
        s16x8 wl = *(const s16x8*)(WlT + aoff);
        acc[mt][0] = MFMA16(wh, xh0, acc[mt][0]);
        acc[mt][0] = MFMA16(wl, xh0, acc[mt][0]);
        acc[mt][0] = MFMA16(wh, xl0, acc[mt][0]);
        acc[mt][1] = MFMA16(wh, xh1, acc[mt][1]);
        acc[mt][1] = MFMA16(wl, xh1, acc[mt][1]);
        acc[mt][1] = MFMA16(wh, xl1, acc[mt][1]);
      }
    }
#pragma unroll
    for (int mt = 0; mt < 4; mt++) {
#pragma unroll
      for (int r = 0; r < 4; r++) {
        int drow = wv * 64 + mt * 16 + quad * 4 + r;
        float bb = bv[drow];
#pragma unroll
        for (int nt = 0; nt < 2; nt++) {
          ((_Float16*)Vt)[(bidx * 256 + drow) * 8192 + tl0 + nt * 16 + lq] =
              (_Float16)(acc[mt][nt][r] + bb);
        }
      }
    }
  }
}

// ---------------- kernel 3: flash attention (fp16, q-block 128, 32x32) ------
// 256 blocks = 128 q-tiles x 2 s-blocks. 8 waves = 4 strips (32 q) x 2 shalf.
// Changes vs the 387us version:
//  - P never touches LDS: packed to f16 in-register + __shfl_xor(.,32) to
//    exchange the partner half-lane's s-slots (C layout: col=q=lane&31,
//    row=s=(r&3)+8*(r>>2)+4*hh) -> PV B-fragments built in registers.
//  - K/V double-buffered in LDS (2x(33792+36864)=141312 B, fits 160KB; we're
//    register-capped at 1 block/CU anyway) -> ONE barrier per iter.
//  - All global/LDS staging addresses hoisted: s=16i+(tid>>5), g=tid&31 etc.
//    collapse to 2 advancing pointers + compile-time offsets.
//  - s_setprio(1) around both MFMA clusters.
// Register budget unchanged (~128 VGPR + 128 AGPR); launch_bounds(512,2).
__global__ __launch_bounds__(512, 2)
void attn_kernel(const short* __restrict__ Qf, const short* __restrict__ Kf,
                 const short* __restrict__ Vt,
                 float* __restrict__ out, float* __restrict__ O1,
                 float* __restrict__ Mlg) {
  __shared__ short sm[70656];          // 141312 B: KL0|KL1|VtL0|VtL1
  int tid = threadIdx.x;
  int lane = tid & 63, wv = tid >> 6;
  int lq32 = lane & 31, hh = lane >> 5, h8 = hh * 8;
  int strip = wv & 3, sh = wv >> 2;
  int blk = blockIdx.x;
  int qt = blk >> 1, sblk = blk & 1;
  int row0g = qt * 128;
  int b = row0g >> 13;
  int sbase = b * 8192 + sblk * 4096;

  // Q fragments (B-operand): q = strip*32 + lq32, k = st*16 + h8 + j
  f16x8 qf[16];
  {
    const _Float16* qrow =
        (const _Float16*)Qf + (size_t)(row0g + strip * 32 + lq32) * 256 + h8;
#pragma unroll
    for (int st = 0; st < 16; st++) qf[st] = *(const f16x8*)(qrow + st * 16);
  }
  float m_ = -__builtin_inff();        // per-lane q
  float l_ = 0.f;
  f32x16 Oacc[8];                      // O^T[d = dt*32 + row][q]
#pragma unroll
  for (int dt = 0; dt < 8; dt++)
#pragma unroll
    for (int i = 0; i < 16; i++) Oacc[dt][i] = 0.f;

  // hoisted staging addresses: load i covers K row 16i+(tid>>5), granule
  // tid&31; V row 64i+(tid>>3), granule tid&7. Pointers advance per tile.
  const short* kb = Kf + (size_t)(sbase + (tid >> 5)) * 256 + (tid & 31) * 8;
  const short* vb = Vt + (size_t)(b * 256 + (tid >> 3)) * 8192 +
                    sblk * 4096 + (tid & 7) * 8;
  int koff0 = (tid >> 5) * 264 + (tid & 31) * 8;            // KL0 base = 0
  int voff0 = 33792 + (tid >> 3) * 72 + (tid & 7) * 8;      // VtL0 base
  int krow = (sh * 32 + lq32) * 264 + h8;
  int vrow0 = 33792 + lq32 * 72 + sh * 32 + h8;

  u32x4 k_r[4], vt_r[4];
  // prefetch tile 0
#pragma unroll
  for (int i = 0; i < 4; i++) {
    k_r[i] = *(const u32x4*)(kb + i * 4096);
    vt_r[i] = *(const u32x4*)(vb + (size_t)i * 524288);
  }
  kb += 16384;
  vb += 64;
  // commit tile 0 -> buf0
#pragma unroll
  for (int i = 0; i < 4; i++) {
    *(u32x4*)&sm[koff0 + i * 4224] = k_r[i];
    *(u32x4*)&sm[voff0 + i * 4608] = vt_r[i];
  }
  // prefetch tile 1
#pragma unroll
  for (int i = 0; i < 4; i++) {
    k_r[i] = *(const u32x4*)(kb + i * 4096);
    vt_r[i] = *(const u32x4*)(vb + (size_t)i * 524288);
  }
  kb += 16384;
  vb += 64;
  __syncthreads();

  for (int it = 0; it < 64; it++) {
    int cub = it & 1;
    // commit tile it+1 into the back buffer (safe: back buffer's previous
    // readers all passed the barrier ending iter it-1)
    if (it <= 62) {
      int kc = (cub ^ 1) * 16896 + koff0;
      int vc = (cub ^ 1) * 18432 + voff0;
#pragma unroll
      for (int i = 0; i < 4; i++) {
        *(u32x4*)&sm[kc + i * 4224] = k_r[i];
        *(u32x4*)&sm[vc + i * 4608] = vt_r[i];
      }
    }
    // prefetch tile it+2 (latency hidden by this iter's compute + barrier)
    if (it <= 61) {
#pragma unroll
      for (int i = 0; i < 4; i++) {
        k_r[i] = *(const u32x4*)(kb + i * 4096);
        vt_r[i] = *(const u32x4*)(vb + (size_t)i * 524288);
      }
      kb += 16384;
      vb += 64;
    }

    // S^T = K Q^T over wave's 32 s x 32 q (single-term fp16)
    f32x16 sacc;
#pragma unroll
    for (int i = 0; i < 16; i++) sacc[i] = 0.f;
    const short* KL = sm + cub * 16896;
    __builtin_amdgcn_s_setprio(1);
#pragma unroll
    for (int st = 0; st < 16; st++) {
      f16x8 kf = *(const f16x8*)&KL[krow + st * 16];
      sacc = MFMA32H(kf, qf[st], sacc);
    }
    __builtin_amdgcn_s_setprio(0);

    // in-lane online softmax (16 regs + partner half-wave)
    float mx = sacc[0];
#pragma unroll
    for (int i = 1; i < 16; i++) mx = fmaxf(mx, sacc[i]);
    mx = fmaxf(mx, __shfl_xor(mx, 32));
    float mn = fmaxf(m_, mx);
    float alpha = __expf(m_ - mn);
    m_ = mn;
    float rs = 0.f;
#pragma unroll
    for (int i = 0; i < 16; i++) {
      sacc[i] = __expf(sacc[i] - mn);
      rs += sacc[i];
    }
    rs += __shfl_xor(rs, 32);
    l_ = l_ * alpha + rs;

    // P -> PV B-fragments fully in registers.
    // Lane (q=lq32, hh) holds s = (r&3) + 8*(r>>2) + 4*hh for r=0..15.
    // pf0 needs s = 8hh+0..7, pf1 needs s = 16+8hh+0..7; the missing 4-run
    // lives in lane^32. One shfl per output word-pair.
    unsigned pa0 = pk16(sacc[0], sacc[1]), pa1 = pk16(sacc[2], sacc[3]);
    unsigned pb0 = pk16(sacc[4], sacc[5]), pb1 = pk16(sacc[6], sacc[7]);
    unsigned pc0 = pk16(sacc[8], sacc[9]), pc1 = pk16(sacc[10], sacc[11]);
    unsigned pd0 = pk16(sacc[12], sacc[13]), pd1 = pk16(sacc[14], sacc[15]);
    unsigned q0 = (unsigned)__shfl_xor((int)(hh ? pa0 : pb0), 32);
    unsigned q1 = (unsigned)__shfl_xor((int)(hh ? pa1 : pb1), 32);
    unsigned q2 = (unsigned)__shfl_xor((int)(hh ? pc0 : pd0), 32);
    unsigned q3 = (unsigned)__shfl_xor((int)(hh ? pc1 : pd1), 32);
    u32x4 P0 = hh ? (u32x4){q0, q1, pb0, pb1} : (u32x4){pa0, pa1, q0, q1};
    u32x4 P1 = hh ? (u32x4){q2, q3, pd0, pd1} : (u32x4){pc0, pc1, q2, q3};
    f16x8 pf0 = __builtin_bit_cast(f16x8, P0);
    f16x8 pf1 = __builtin_bit_cast(f16x8, P1);

    // rescale O^T (in-lane per q); skip when wave-uniform no-op
    if (!__all(alpha == 1.f)) {
#pragma unroll
      for (int dt = 0; dt < 8; dt++) Oacc[dt] = Oacc[dt] * alpha;
    }
    // O^T += V P^T (A = V rows, B = P in registers)
    const short* VL = sm + cub * 18432;
    __builtin_amdgcn_s_setprio(1);
#pragma unroll
    for (int dt = 0; dt < 8; dt++) {
      const short* vr = VL + vrow0 + dt * 2304;
      f16x8 vf0 = *(const f16x8*)vr;
      f16x8 vf1 = *(const f16x8*)(vr + 16);
      Oacc[dt] = MFMA32H(vf0, pf0, Oacc[dt]);
      Oacc[dt] = MFMA32H(vf1, pf1, Oacc[dt]);
    }
    __builtin_amdgcn_s_setprio(0);
    __syncthreads();
  }

  // ---- epilogue: shalf pair-merge + coalesced partial write ----
  // Msh sits at byte 67584 = start of VtL0; last iter (cub=1) read only
  // KL1/VtL1, so this pre-barrier write cannot race loop readers.
  float* smf = (float*)sm;             // Ob: 4 strips x [32 q][132] f32
  float* Msh = smf + 16896;            // m [2][4][32], l at +256
  if (lane < 32) {
    Msh[(sh * 4 + strip) * 32 + lq32] = m_;
    Msh[256 + (sh * 4 + strip) * 32 + lq32] = l_;
  }
  __syncthreads();
  float m1 = Msh[((1 - sh) * 4 + strip) * 32 + lq32];
  float l1 = Msh[256 + ((1 - sh) * 4 + strip) * 32 + lq32];
  float mm = fmaxf(m_, m1);
  float e0 = __expf(m_ - mm);
  float e1 = __expf(m1 - mm);
  float* Opart = (sblk == 0) ? out : O1;
  if (sh == 0 && lane < 32) {          // combined (m, l) for this s-block
    float lsum = l_ * e0 + l1 * e1;
    int rowq = row0g + strip * 32 + lq32;
    Mlg[sblk * 32768 + rowq * 2] = mm;
    Mlg[sblk * 32768 + rowq * 2 + 1] = lsum;
  }
  float* Ob = smf + strip * 4224;      // 32*132
#pragma unroll
  for (int hd = 0; hd < 2; hd++) {
    __syncthreads();
    if (sh == 1) {
#pragma unroll
      for (int dt2 = 0; dt2 < 4; dt2++) {
        int dt = hd * 4 + dt2;
#pragma unroll
        for (int g = 0; g < 4; g++) {
          f32x4 v = {Oacc[dt][g * 4], Oacc[dt][g * 4 + 1],
                     Oacc[dt][g * 4 + 2], Oacc[dt][g * 4 + 3]};
          *(f32x4*)&Ob[lq32 * 132 + dt2 * 32 + 8 * g + 4 * hh] = v;
        }
      }
    }
    __syncthreads();
    if (sh == 0) {
#pragma unroll
      for (int dt2 = 0; dt2 < 4; dt2++) {
        int dt = hd * 4 + dt2;
#pragma unroll
        for (int g = 0; g < 4; g++) {
          float* ad = &Ob[lq32 * 132 + dt2 * 32 + 8 * g + 4 * hh];
          f32x4 o1 = *(f32x4*)ad;
          f32x4 cmb;
#pragma unroll
          for (int j = 0; j < 4; j++)
            cmb[j] = Oacc[dt][g * 4 + j] * e0 + o1[j] * e1;
          *(f32x4*)ad = cmb;
        }
      }
    }
    __syncthreads();
    // cooperative coalesced write of this d-half: 128 q x 32 f32x4 groups
#pragma unroll
    for (int i = 0; i < 8; i++) {
      int idx = i * 512 + tid;
      int q = idx >> 5, gb = idx & 31;
      f32x4 v = *(f32x4*)&smf[(q >> 5) * 4224 + (q & 31) * 132 + gb * 4];
      *(f32x4*)&Opart[(size_t)(row0g + q) * 256 + hd * 128 + gb * 4] = v;
    }
  }
}

// ---------------- kernel 4: s-split merge ----------------
__global__ void merge_kernel(const float* __restrict__ O1,
                             const float* __restrict__ Mlg,
                             float* __restrict__ out) {
  int idx = blockIdx.x * 256 + threadIdx.x;   // 4096 blocks
  int q = idx >> 6, dg = idx & 63;
  float m0 = Mlg[q * 2], l0 = Mlg[q * 2 + 1];
  float m1 = Mlg[32768 + q * 2], l1 = Mlg[32768 + q * 2 + 1];
  float mm = fmaxf(m0, m1);
  float e0 = __expf(m0 - mm), e1 = __expf(m1 - mm);
  float inv = 1.f / (l0 * e0 + l1 * e1);
  f32x4 a = *(const f32x4*)(out + (size_t)q * 256 + dg * 4);
  f32x4 bb = *(const f32x4*)(O1 + (size_t)q * 256 + dg * 4);
  f32x4 r;
#pragma unroll
  for (int j = 0; j < 4; j++) r[j] = (a[j] * e0 + bb[j] * e1) * inv;
  *(f32x4*)(out + (size_t)q * 256 + dg * 4) = r;
}

// ---------------- launcher ----------------
extern "C" void kernel_launch(void* const* d_in, const int* in_sizes, int n_in,
                              void* d_out, int out_size, void* d_ws, size_t ws_size,
                              hipStream_t stream) {
  const float* x  = (const float*)d_in[0];
  const float* Wq = (const float*)d_in[1];
  const float* bq = (const float*)d_in[2];
  const float* Wk = (const float*)d_in[3];
  const float* bk = (const float*)d_in[4];
  const float* Wv = (const float*)d_in[5];
  const float* bv = (const float*)d_in[6];
  float* out = (float*)d_out;
  short* ws = (short*)d_ws;
  // ws layout (shorts): wt 393216 | Qf 4194304 | Kf 4194304 | Vt 4194304 |
  // O1 (float 4194304) at short-offset 12976128. Mlg aliases wt (dead after
  // qkv). Total = 42,729,472 B (same as the validated R4 footprint).
  short* wt = ws;
  short* Qf = ws + 393216;
  short* Kf = Qf + 4194304;
  short* Vt = Kf + 4194304;
  float* O1  = (float*)(ws + 12976128);
  float* Mlg = (float*)ws;
  hipLaunchKernelGGL(wtrans_kernel, dim3(768), dim3(256), 0, stream, Wq, Wk, Wv, wt);
  hipLaunchKernelGGL(qkv_kernel, dim3(512), dim3(256), 0, stream,
                     x, bq, bk, bv, wt, Qf, Kf, Vt);
  hipLaunchKernelGGL(attn_kernel, dim3(256), dim3(512), 0, stream,
                     Qf, Kf, Vt, out, O1, Mlg);
  hipLaunchKernelGGL(merge_kernel, dim3(4096), dim3(256), 0, stream,
                     O1, Mlg, out);
}

// Round 3
// 302.959 us; speedup vs baseline: 1.2783x; 1.1685x over previous
//
#include <hip/hip_runtime.h>
#include <stdint.h>

// ---- types ----
typedef __attribute__((ext_vector_type(4))) float f32x4;
typedef __attribute__((ext_vector_type(16))) float f32x16;
typedef __attribute__((ext_vector_type(8))) short s16x8;
typedef __attribute__((ext_vector_type(4))) short s16x4;
typedef __attribute__((ext_vector_type(4))) unsigned int u32x4;
typedef __attribute__((ext_vector_type(8))) _Float16 f16x8;
typedef __attribute__((ext_vector_type(4))) _Float16 f16x4;
typedef __attribute__((ext_vector_type(2))) _Float16 f16x2;

#define MFMA16(a, b, c) __builtin_amdgcn_mfma_f32_16x16x32_bf16((a), (b), (c), 0, 0, 0)
#define MFMA32H(a, b, c) __builtin_amdgcn_mfma_f32_32x32x16_f16((a), (b), (c), 0, 0, 0)

// B=2, T=8192, D=256; rows = B*T = 16384 flat.

__device__ __forceinline__ unsigned short f2bf(float f) {
  unsigned int u = __float_as_uint(f);
  u += 0x7FFFu + ((u >> 16) & 1u);  // RNE
  return (unsigned short)(u >> 16);
}
__device__ __forceinline__ float bf2f(unsigned short h) {
  return __uint_as_float(((unsigned int)h) << 16);
}
__device__ __forceinline__ unsigned pk16(float a, float b) {
  f16x2 p;
  p[0] = (_Float16)a;  // RNE
  p[1] = (_Float16)b;
  return __builtin_bit_cast(unsigned, p);
}

// async global->LDS, 16 B per lane; gptr per-lane, lptr wave-uniform base.
typedef const __attribute__((address_space(1))) void gas_void;
typedef __attribute__((address_space(3))) void las_void;
__device__ __forceinline__ void glds16(const void* g, void* l) {
  __builtin_amdgcn_global_load_lds((gas_void*)g, (las_void*)l, 16, 0, 0);
}

// ---------------- kernel 1: weight transpose + hi/lo split (bf16) -----------
__global__ void wtrans_kernel(const float* __restrict__ Wq,
                              const float* __restrict__ Wk,
                              const float* __restrict__ Wv,
                              short* __restrict__ wt) {
  int idx = blockIdx.x * 256 + threadIdx.x;   // 768 blocks * 256
  int w = idx >> 16;
  int rc = idx & 65535;
  int d = rc >> 8;
  int n = rc & 255;
  const float* Ws = (w == 0) ? Wq : ((w == 1) ? Wk : Wv);
  float v = Ws[rc];
  unsigned short hi = f2bf(v);
  unsigned short lo = f2bf(v - bf2f(hi));
  short* th = wt + w * 131072;
  th[n * 256 + d] = (short)hi;
  th[65536 + n * 256 + d] = (short)lo;
}

// ---------------- kernel 2: QKV projection (3-term bf16 MFMA) ----------------
// Outputs fp16: Qf [16384][256] row-major.
// Kf fragment-major for attn glds: short idx =
//   (row>>6)*16384 + (col>>4)*1024 + ((row>>5)&1)*512 + (row&31)*16
//   + ((col>>3)&1)*8 + (col&7)
// Vt fragment-major: short idx = b*2097152 + (s>>6)*16384 + (d>>5)*2048
//   + ((s>>5)&1)*1024 + sf*512 + (d&31)*16 + ((s>>3)&1)*8 + (s&7)   [sf=(s>>4)&1]
__global__ __launch_bounds__(256, 2)
void qkv_kernel(const float* __restrict__ x,
                const float* __restrict__ bq,
                const float* __restrict__ bk,
                const float* __restrict__ bv,
                const short* __restrict__ wt,
                short* __restrict__ Qf, short* __restrict__ Kf,
                short* __restrict__ Vt) {
  __shared__ short X[16896];
  int tid = threadIdx.x;
  int r0 = blockIdx.x * 32;
  int bidx = r0 >> 13;
  int tl0 = r0 & 8191;
#pragma unroll
  for (int i = 0; i < 8; i++) {
    int E = i * 1024 + tid * 4;
    int r = E >> 8, col = E & 255;
    f32x4 v = *(const f32x4*)(x + (size_t)(r0 + r) * 256 + col);
    s16x4 h, lo;
#pragma unroll
    for (int j = 0; j < 4; j++) {
      unsigned short hh = f2bf(v[j]);
      h[j] = (short)hh;
      lo[j] = (short)f2bf(v[j] - bf2f(hh));
    }
    *(s16x4*)&X[r * 264 + col] = h;
    *(s16x4*)&X[8448 + r * 264 + col] = lo;
  }
  __syncthreads();

  int lane = tid & 63, wv = tid >> 6;
  int quad = lane >> 4, lq = lane & 15;

  {
    int strip = wv & 1;
    const short* WhT = wt + ((wv < 2) ? 0 : 131072);
    const short* WlT = WhT + 65536;
    f32x4 acc[16];
#pragma unroll
    for (int nt = 0; nt < 16; nt++) acc[nt] = (f32x4){0.f, 0.f, 0.f, 0.f};
    int arow = (strip * 16 + lq) * 264 + quad * 8;
#pragma unroll
    for (int c = 0; c < 8; c++) {
      s16x8 xh = *(const s16x8*)&X[arow + c * 32];
      s16x8 xl = *(const s16x8*)&X[8448 + arow + c * 32];
#pragma unroll
      for (int nt = 0; nt < 16; nt++) {
        int boff = (nt * 16 + lq) * 256 + c * 32 + quad * 8;
        s16x8 wh = *(const s16x8*)(WhT + boff);
        s16x8 wl = *(const s16x8*)(WlT + boff);
        acc[nt] = MFMA16(xh, wh, acc[nt]);
        acc[nt] = MFMA16(xl, wh, acc[nt]);
        acc[nt] = MFMA16(xh, wl, acc[nt]);
      }
    }
    const float* bias = (wv < 2) ? bq : bk;
    if (wv < 2) {                 // Q: row-major
      _Float16* Of = (_Float16*)Qf;
#pragma unroll
      for (int nt = 0; nt < 16; nt++) {
        int col = nt * 16 + lq;
        float bb = bias[col];
#pragma unroll
        for (int r = 0; r < 4; r++) {
          int row = r0 + strip * 16 + quad * 4 + r;
          Of[row * 256 + col] = (_Float16)(acc[nt][r] + bb);
        }
      }
    } else {                      // K: fragment-major
      _Float16* Of = (_Float16*)Kf;
      int stile = r0 >> 6;        // rows r0..r0+31 share tile & s-half
      int shh = (r0 >> 5) & 1;
      int kb0 = stile * 16384 + shh * 512;
#pragma unroll
      for (int nt = 0; nt < 16; nt++) {
        int col = nt * 16 + lq;
        float bb = bias[col];
        int kc = kb0 + (col >> 4) * 1024 + ((col >> 3) & 1) * 8 + (col & 7);
#pragma unroll
        for (int r = 0; r < 4; r++) {
          int s32 = strip * 16 + quad * 4 + r;
          Of[kc + s32 * 16] = (_Float16)(acc[nt][r] + bb);
        }
      }
    }
  }
  {
    const short* WhT = wt + 262144;
    const short* WlT = wt + 327680;
    f32x4 acc[4][2];
#pragma unroll
    for (int mt = 0; mt < 4; mt++)
#pragma unroll
      for (int nt = 0; nt < 2; nt++) acc[mt][nt] = (f32x4){0.f, 0.f, 0.f, 0.f};
#pragma unroll
    for (int c = 0; c < 8; c++) {
      int co = c * 32 + quad * 8;
      s16x8 xh0 = *(const s16x8*)&X[lq * 264 + co];
      s16x8 xl0 = *(const s16x8*)&X[8448 + lq * 264 + co];
      s16x8 xh1 = *(const s16x8*)&X[(16 + lq) * 264 + co];
      s16x8 xl1 = *(const s16x8*)&X[8448 + (16 + lq) * 264 + co];
#pragma unroll
      for (int mt = 0; mt < 4; mt++) {
        int aoff = (wv * 64 + mt * 16 + lq) * 256 + co;
        s16x8 wh = *(const s16x8*)(WhT + aoff);
        s16x8 wl = *(const s16x8*)(WlT + aoff);
        acc[mt][0] = MFMA16(wh, xh0, acc[mt][0]);
        acc[mt][0] = MFMA16(wl, xh0, acc[mt][0]);
        acc[mt][0] = MFMA16(wh, xl0, acc[mt][0]);
        acc[mt][1] = MFMA16(wh, xh1, acc[mt][1]);
        acc[mt][1] = MFMA16(wl, xh1, acc[mt][1]);
        acc[mt][1] = MFMA16(wh, xl1, acc[mt][1]);
      }
    }
    // V: fragment-major. s = tl0 + nt*16 + lq (tl0 % 32 == 0, nt*16+lq < 32)
    _Float16* Vg = (_Float16*)Vt;
    int vb0 = bidx * 2097152 + (tl0 >> 6) * 16384 + ((tl0 >> 5) & 1) * 1024 +
              ((lq >> 3) & 1) * 8 + (lq & 7);
#pragma unroll
    for (int mt = 0; mt < 4; mt++) {
#pragma unroll
      for (int r = 0; r < 4; r++) {
        int drow = wv * 64 + mt * 16 + quad * 4 + r;
        float bb = bv[drow];
        int vc = vb0 + (drow >> 5) * 2048 + (drow & 31) * 16;
#pragma unroll
        for (int nt = 0; nt < 2; nt++) {
          Vg[vc + nt * 512] = (_Float16)(acc[mt][nt][r] + bb);
        }
      }
    }
  }
}

// ---------------- kernel 3: flash attention (fp16, q-block 128, 32x32) ------
// 256 blocks = 128 q-tiles x 2 s-blocks. 8 waves = 4 strips (32 q) x 2 shalf.
// Changes vs 217us version:
//  - K/V staged via global_load_lds from fragment-major global layouts:
//    zero staging VGPRs, zero ds_writes, coalesced 1024-B wave loads,
//    conflict-free unpadded LDS (131072 B double-buffered).
//  - Schedule: [syncthreads (drains tile-it glds) | issue tile it+1 | compute].
//  - T13 defer-max (THR=8): Oacc rescale only when __any(mx > m_+8).
//  - max3-shaped reduction tree for row max.
__global__ __launch_bounds__(512, 2)
void attn_kernel(const short* __restrict__ Qf, const short* __restrict__ Kf,
                 const short* __restrict__ Vt,
                 float* __restrict__ out, float* __restrict__ O1,
                 float* __restrict__ Mlg) {
  __shared__ short sm[65536];          // 131072 B: buf{0,1} x [K 32KB | V 32KB]
  int tid = threadIdx.x;
  int lane = tid & 63, wv = tid >> 6;
  int lq32 = lane & 31, hh = lane >> 5, h8 = hh * 8;
  int strip = wv & 3, sh = wv >> 2;
  int blk = blockIdx.x;
  int qt = blk >> 1, sblk = blk & 1;
  int row0g = qt * 128;
  int b = row0g >> 13;

  // Q fragments (B-operand): q = strip*32 + lq32, k = st*16 + h8 + j
  f16x8 qf[16];
  {
    const _Float16* qrow =
        (const _Float16*)Qf + (size_t)(row0g + strip * 32 + lq32) * 256 + h8;
#pragma unroll
    for (int st = 0; st < 16; st++) qf[st] = *(const f16x8*)(qrow + st * 16);
  }
  float m_ = -__builtin_inff();        // per-lane q
  float l_ = 0.f;
  f32x16 Oacc[8];                      // O^T[d = dt*32 + row][q]
#pragma unroll
  for (int dt = 0; dt < 8; dt++)
#pragma unroll
    for (int i = 0; i < 16; i++) Oacc[dt][i] = 0.f;

  // glds bases: per tile 32768 B; wave wv covers chunks wv*4..wv*4+3 (K and V)
  const char* gK = (const char*)Kf +
                   ((size_t)(b * 128 + sblk * 64) * 32768) + wv * 4096 + lane * 16;
  const char* gV = (const char*)Vt + (size_t)b * 4194304 +
                   (size_t)sblk * 2097152 + wv * 4096 + lane * 16;
  char* lds0 = (char*)sm;

  // issue tile 0 -> buf0
#pragma unroll
  for (int i = 0; i < 4; i++) {
    glds16(gK + i * 1024, lds0 + wv * 4096 + i * 1024);
    glds16(gV + i * 1024, lds0 + 32768 + wv * 4096 + i * 1024);
  }
  gK += 32768;
  gV += 32768;

  for (int it = 0; it < 64; it++) {
    int cub = it & 1;
    __syncthreads();                   // drains tile-it glds (vmcnt) + barrier
    if (it < 63) {                     // issue tile it+1 -> back buffer
      char* lb = lds0 + (cub ^ 1) * 65536;
#pragma unroll
      for (int i = 0; i < 4; i++) {
        glds16(gK + i * 1024, lb + wv * 4096 + i * 1024);
        glds16(gV + i * 1024, lb + 32768 + wv * 4096 + i * 1024);
      }
      gK += 32768;
      gV += 32768;
    }

    // S^T = K Q^T over wave's 32 s x 32 q (single-term fp16)
    f32x16 sacc;
#pragma unroll
    for (int i = 0; i < 16; i++) sacc[i] = 0.f;
    const short* KL = sm + cub * 32768 + sh * 512;
    __builtin_amdgcn_s_setprio(1);
#pragma unroll
    for (int st = 0; st < 16; st++) {
      f16x8 kf = *(const f16x8*)&KL[st * 1024 + lq32 * 16 + h8];
      sacc = MFMA32H(kf, qf[st], sacc);
    }
    __builtin_amdgcn_s_setprio(0);

    // online softmax: max3-friendly tree + defer-max (THR=8)
    float a0 = fmaxf(fmaxf(sacc[0], sacc[1]), sacc[2]);
    float a1 = fmaxf(fmaxf(sacc[3], sacc[4]), sacc[5]);
    float a2 = fmaxf(fmaxf(sacc[6], sacc[7]), sacc[8]);
    float a3 = fmaxf(fmaxf(sacc[9], sacc[10]), sacc[11]);
    float a4 = fmaxf(fmaxf(sacc[12], sacc[13]), sacc[14]);
    float b0 = fmaxf(fmaxf(a0, a1), a2);
    float b1 = fmaxf(fmaxf(a3, a4), sacc[15]);
    float mx = fmaxf(b0, b1);
    mx = fmaxf(mx, __shfl_xor(mx, 32));
    if (__any(mx > m_ + 8.f)) {        // rescale only on real growth
      float mn = fmaxf(m_, mx);
      float alpha = __expf(m_ - mn);
      m_ = mn;
      l_ *= alpha;
#pragma unroll
      for (int dt = 0; dt < 8; dt++) Oacc[dt] = Oacc[dt] * alpha;
    }
    float rs = 0.f;
#pragma unroll
    for (int i = 0; i < 16; i++) {
      sacc[i] = __expf(sacc[i] - m_);
      rs += sacc[i];
    }
    rs += __shfl_xor(rs, 32);
    l_ += rs;

    // P -> PV B-fragments fully in registers.
    // Lane (q=lq32, hh) holds s = (r&3) + 8*(r>>2) + 4*hh for r=0..15.
    unsigned pa0 = pk16(sacc[0], sacc[1]), pa1 = pk16(sacc[2], sacc[3]);
    unsigned pb0 = pk16(sacc[4], sacc[5]), pb1 = pk16(sacc[6], sacc[7]);
    unsigned pc0 = pk16(sacc[8], sacc[9]), pc1 = pk16(sacc[10], sacc[11]);
    unsigned pd0 = pk16(sacc[12], sacc[13]), pd1 = pk16(sacc[14], sacc[15]);
    unsigned q0 = (unsigned)__shfl_xor((int)(hh ? pa0 : pb0), 32);
    unsigned q1 = (unsigned)__shfl_xor((int)(hh ? pa1 : pb1), 32);
    unsigned q2 = (unsigned)__shfl_xor((int)(hh ? pc0 : pd0), 32);
    unsigned q3 = (unsigned)__shfl_xor((int)(hh ? pc1 : pd1), 32);
    u32x4 P0 = hh ? (u32x4){q0, q1, pb0, pb1} : (u32x4){pa0, pa1, q0, q1};
    u32x4 P1 = hh ? (u32x4){q2, q3, pd0, pd1} : (u32x4){pc0, pc1, q2, q3};
    f16x8 pf0 = __builtin_bit_cast(f16x8, P0);
    f16x8 pf1 = __builtin_bit_cast(f16x8, P1);

    // O^T += V P^T (A = V rows from LDS, B = P in registers)
    const short* VL = sm + cub * 32768 + 16384 + sh * 1024;
    __builtin_amdgcn_s_setprio(1);
#pragma unroll
    for (int dt = 0; dt < 8; dt++) {
      f16x8 vf0 = *(const f16x8*)&VL[dt * 2048 + lq32 * 16 + h8];
      f16x8 vf1 = *(const f16x8*)&VL[dt * 2048 + 512 + lq32 * 16 + h8];
      Oacc[dt] = MFMA32H(vf0, pf0, Oacc[dt]);
      Oacc[dt] = MFMA32H(vf1, pf1, Oacc[dt]);
    }
    __builtin_amdgcn_s_setprio(0);
  }
  __syncthreads();                     // all loop readers done before smf reuse

  // ---- epilogue: shalf pair-merge + coalesced partial write ----
  float* smf = (float*)sm;             // Ob: 4 strips x [32 q][132] f32
  float* Msh = smf + 16896;            // m [2][4][32], l at +256
  if (lane < 32) {
    Msh[(sh * 4 + strip) * 32 + lq32] = m_;
    Msh[256 + (sh * 4 + strip) * 32 + lq32] = l_;
  }
  __syncthreads();
  float m1 = Msh[((1 - sh) * 4 + strip) * 32 + lq32];
  float l1 = Msh[256 + ((1 - sh) * 4 + strip) * 32 + lq32];
  float mm = fmaxf(m_, m1);
  float e0 = __expf(m_ - mm);
  float e1 = __expf(m1 - mm);
  float* Opart = (sblk == 0) ? out : O1;
  if (sh == 0 && lane < 32) {          // combined (m, l) for this s-block
    float lsum = l_ * e0 + l1 * e1;
    int rowq = row0g + strip * 32 + lq32;
    Mlg[sblk * 32768 + rowq * 2] = mm;
    Mlg[sblk * 32768 + rowq * 2 + 1] = lsum;
  }
  float* Ob = smf + strip * 4224;      // 32*132
#pragma unroll
  for (int hd = 0; hd < 2; hd++) {
    __syncthreads();
    if (sh == 1) {
#pragma unroll
      for (int dt2 = 0; dt2 < 4; dt2++) {
        int dt = hd * 4 + dt2;
#pragma unroll
        for (int g = 0; g < 4; g++) {
          f32x4 v = {Oacc[dt][g * 4], Oacc[dt][g * 4 + 1],
                     Oacc[dt][g * 4 + 2], Oacc[dt][g * 4 + 3]};
          *(f32x4*)&Ob[lq32 * 132 + dt2 * 32 + 8 * g + 4 * hh] = v;
        }
      }
    }
    __syncthreads();
    if (sh == 0) {
#pragma unroll
      for (int dt2 = 0; dt2 < 4; dt2++) {
        int dt = hd * 4 + dt2;
#pragma unroll
        for (int g = 0; g < 4; g++) {
          float* ad = &Ob[lq32 * 132 + dt2 * 32 + 8 * g + 4 * hh];
          f32x4 o1 = *(f32x4*)ad;
          f32x4 cmb;
#pragma unroll
          for (int j = 0; j < 4; j++)
            cmb[j] = Oacc[dt][g * 4 + j] * e0 + o1[j] * e1;
          *(f32x4*)ad = cmb;
        }
      }
    }
    __syncthreads();
    // cooperative coalesced write of this d-half: 128 q x 32 f32x4 groups
#pragma unroll
    for (int i = 0; i < 8; i++) {
      int idx = i * 512 + tid;
      int q = idx >> 5, gb = idx & 31;
      f32x4 v = *(f32x4*)&smf[(q >> 5) * 4224 + (q & 31) * 132 + gb * 4];
      *(f32x4*)&Opart[(size_t)(row0g + q) * 256 + hd * 128 + gb * 4] = v;
    }
  }
}

// ---------------- kernel 4: s-split merge ----------------
__global__ void merge_kernel(const float* __restrict__ O1,
                             const float* __restrict__ Mlg,
                             float* __restrict__ out) {
  int idx = blockIdx.x * 256 + threadIdx.x;   // 4096 blocks
  int q = idx >> 6, dg = idx & 63;
  float m0 = Mlg[q * 2], l0 = Mlg[q * 2 + 1];
  float m1 = Mlg[32768 + q * 2], l1 = Mlg[32768 + q * 2 + 1];
  float mm = fmaxf(m0, m1);
  float e0 = __expf(m0 - mm), e1 = __expf(m1 - mm);
  float inv = 1.f / (l0 * e0 + l1 * e1);
  f32x4 a = *(const f32x4*)(out + (size_t)q * 256 + dg * 4);
  f32x4 bb = *(const f32x4*)(O1 + (size_t)q * 256 + dg * 4);
  f32x4 r;
#pragma unroll
  for (int j = 0; j < 4; j++) r[j] = (a[j] * e0 + bb[j] * e1) * inv;
  *(f32x4*)(out + (size_t)q * 256 + dg * 4) = r;
}

// ---------------- launcher ----------------
extern "C" void kernel_launch(void* const* d_in, const int* in_sizes, int n_in,
                              void* d_out, int out_size, void* d_ws, size_t ws_size,
                              hipStream_t stream) {
  const float* x  = (const float*)d_in[0];
  const float* Wq = (const float*)d_in[1];
  const float* bq = (const float*)d_in[2];
  const float* Wk = (const float*)d_in[3];
  const float* bk = (const float*)d_in[4];
  const float* Wv = (const float*)d_in[5];
  const float* bv = (const float*)d_in[6];
  float* out = (float*)d_out;
  short* ws = (short*)d_ws;
  // ws layout (shorts): wt 393216 | Qf 4194304 | Kf 4194304 | Vt 4194304 |
  // O1 (float 4194304) at short-offset 12976128. Mlg aliases wt (dead after
  // qkv). Total = 42,729,472 B.
  short* wt = ws;
  short* Qf = ws + 393216;
  short* Kf = Qf + 4194304;
  short* Vt = Kf + 4194304;
  float* O1  = (float*)(ws + 12976128);
  float* Mlg = (float*)ws;
  hipLaunchKernelGGL(wtrans_kernel, dim3(768), dim3(256), 0, stream, Wq, Wk, Wv, wt);
  hipLaunchKernelGGL(qkv_kernel, dim3(512), dim3(256), 0, stream,
                     x, bq, bk, bv, wt, Qf, Kf, Vt);
  hipLaunchKernelGGL(attn_kernel, dim3(256), dim3(512), 0, stream,
                     Qf, Kf, Vt, out, O1, Mlg);
  hipLaunchKernelGGL(merge_kernel, dim3(4096), dim3(256), 0, stream,
                     O1, Mlg, out);
}

// Round 4
// 301.105 us; speedup vs baseline: 1.2862x; 1.0062x over previous
//
#include <hip/hip_runtime.h>
#include <stdint.h>

// ---- types ----
typedef __attribute__((ext_vector_type(4))) float f32x4;
typedef __attribute__((ext_vector_type(16))) float f32x16;
typedef __attribute__((ext_vector_type(8))) short s16x8;
typedef __attribute__((ext_vector_type(4))) short s16x4;
typedef __attribute__((ext_vector_type(4))) unsigned int u32x4;
typedef __attribute__((ext_vector_type(8))) _Float16 f16x8;
typedef __attribute__((ext_vector_type(4))) _Float16 f16x4;
typedef __attribute__((ext_vector_type(2))) _Float16 f16x2;

#define MFMA16(a, b, c) __builtin_amdgcn_mfma_f32_16x16x32_bf16((a), (b), (c), 0, 0, 0)
#define MFMA32H(a, b, c) __builtin_amdgcn_mfma_f32_32x32x16_f16((a), (b), (c), 0, 0, 0)

// B=2, T=8192, D=256; rows = B*T = 16384 flat.

__device__ __forceinline__ unsigned short f2bf(float f) {
  unsigned int u = __float_as_uint(f);
  u += 0x7FFFu + ((u >> 16) & 1u);  // RNE
  return (unsigned short)(u >> 16);
}
__device__ __forceinline__ float bf2f(unsigned short h) {
  return __uint_as_float(((unsigned int)h) << 16);
}
__device__ __forceinline__ unsigned pk16(float a, float b) {
  f16x2 p;
  p[0] = (_Float16)a;  // RNE
  p[1] = (_Float16)b;
  return __builtin_bit_cast(unsigned, p);
}

// async global->LDS, 16 B per lane; gptr per-lane, lptr wave-uniform base.
typedef const __attribute__((address_space(1))) void gas_void;
typedef __attribute__((address_space(3))) void las_void;
__device__ __forceinline__ void glds16(const void* g, void* l) {
  __builtin_amdgcn_global_load_lds((gas_void*)g, (las_void*)l, 16, 0, 0);
}

// ---------------- kernel 1: weight transpose + hi/lo split (bf16) -----------
__global__ void wtrans_kernel(const float* __restrict__ Wq,
                              const float* __restrict__ Wk,
                              const float* __restrict__ Wv,
                              short* __restrict__ wt) {
  int idx = blockIdx.x * 256 + threadIdx.x;   // 768 blocks * 256
  int w = idx >> 16;
  int rc = idx & 65535;
  int d = rc >> 8;
  int n = rc & 255;
  const float* Ws = (w == 0) ? Wq : ((w == 1) ? Wk : Wv);
  float v = Ws[rc];
  unsigned short hi = f2bf(v);
  unsigned short lo = f2bf(v - bf2f(hi));
  short* th = wt + w * 131072;
  th[n * 256 + d] = (short)hi;
  th[65536 + n * 256 + d] = (short)lo;
}

// ---------------- kernel 2: QKV projection (3-term bf16 MFMA) ----------------
// Outputs fp16: Qf [16384][256] row-major.
// Kf fragment-major + bank-swizzle for attn glds; base (pre-swizzle) short idx:
//   (row>>6)*16384 + (col>>4)*1024 + ((row>>5)&1)*512 + (row&31)*16
//   + ((col>>3)&1)*8 + (col&7), then idx ^= ((idx>>6)&1)<<3  [= (row>>2)&1].
// Vt fragment-major + same swizzle: idx = b*2097152 + (s>>6)*16384 + (d>>5)*2048
//   + ((s>>5)&1)*1024 + ((s>>4)&1)*512 + (d&31)*16 + ((s>>3)&1)*8 + (s&7),
//   then idx ^= ((idx>>6)&1)<<3  [= (d>>2)&1].
// The XOR makes 8-lane ds_read_b128 groups tile all 32 banks (R3 had 2-way).
__global__ __launch_bounds__(256, 2)
void qkv_kernel(const float* __restrict__ x,
                const float* __restrict__ bq,
                const float* __restrict__ bk,
                const float* __restrict__ bv,
                const short* __restrict__ wt,
                short* __restrict__ Qf, short* __restrict__ Kf,
                short* __restrict__ Vt) {
  __shared__ short X[16896];
  int tid = threadIdx.x;
  int r0 = blockIdx.x * 32;
  int bidx = r0 >> 13;
  int tl0 = r0 & 8191;
#pragma unroll
  for (int i = 0; i < 8; i++) {
    int E = i * 1024 + tid * 4;
    int r = E >> 8, col = E & 255;
    f32x4 v = *(const f32x4*)(x + (size_t)(r0 + r) * 256 + col);
    s16x4 h, lo;
#pragma unroll
    for (int j = 0; j < 4; j++) {
      unsigned short hh = f2bf(v[j]);
      h[j] = (short)hh;
      lo[j] = (short)f2bf(v[j] - bf2f(hh));
    }
    *(s16x4*)&X[r * 264 + col] = h;
    *(s16x4*)&X[8448 + r * 264 + col] = lo;
  }
  __syncthreads();

  int lane = tid & 63, wv = tid >> 6;
  int quad = lane >> 4, lq = lane & 15;
  int swz8 = (quad & 1) << 3;          // bank-swizzle bit (bit6 of frag idx)

  {
    int strip = wv & 1;
    const short* WhT = wt + ((wv < 2) ? 0 : 131072);
    const short* WlT = WhT + 65536;
    f32x4 acc[16];
#pragma unroll
    for (int nt = 0; nt < 16; nt++) acc[nt] = (f32x4){0.f, 0.f, 0.f, 0.f};
    int arow = (strip * 16 + lq) * 264 + quad * 8;
#pragma unroll
    for (int c = 0; c < 8; c++) {
      s16x8 xh = *(const s16x8*)&X[arow + c * 32];
      s16x8 xl = *(const s16x8*)&X[8448 + arow + c * 32];
#pragma unroll
      for (int nt = 0; nt < 16; nt++) {
        int boff = (nt * 16 + lq) * 256 + c * 32 + quad * 8;
        s16x8 wh = *(const s16x8*)(WhT + boff);
        s16x8 wl = *(const s16x8*)(WlT + boff);
        acc[nt] = MFMA16(xh, wh, acc[nt]);
        acc[nt] = MFMA16(xl, wh, acc[nt]);
        acc[nt] = MFMA16(xh, wl, acc[nt]);
      }
    }
    const float* bias = (wv < 2) ? bq : bk;
    if (wv < 2) {                 // Q: row-major
      _Float16* Of = (_Float16*)Qf;
#pragma unroll
      for (int nt = 0; nt < 16; nt++) {
        int col = nt * 16 + lq;
        float bb = bias[col];
#pragma unroll
        for (int r = 0; r < 4; r++) {
          int row = r0 + strip * 16 + quad * 4 + r;
          Of[row * 256 + col] = (_Float16)(acc[nt][r] + bb);
        }
      }
    } else {                      // K: fragment-major + swizzle
      _Float16* Of = (_Float16*)Kf;
      int stile = r0 >> 6;        // rows r0..r0+31 share tile & s-half
      int shh = (r0 >> 5) & 1;
      int kb0 = stile * 16384 + shh * 512;
#pragma unroll
      for (int nt = 0; nt < 16; nt++) {
        int col = nt * 16 + lq;
        float bb = bias[col];
        int kc = (kb0 + (col >> 4) * 1024 + ((col >> 3) & 1) * 8 + (col & 7)) ^ swz8;
#pragma unroll
        for (int r = 0; r < 4; r++) {
          int s32 = strip * 16 + quad * 4 + r;
          Of[kc + s32 * 16] = (_Float16)(acc[nt][r] + bb);
        }
      }
    }
  }
  {
    const short* WhT = wt + 262144;
    const short* WlT = wt + 327680;
    f32x4 acc[4][2];
#pragma unroll
    for (int mt = 0; mt < 4; mt++)
#pragma unroll
      for (int nt = 0; nt < 2; nt++) acc[mt][nt] = (f32x4){0.f, 0.f, 0.f, 0.f};
#pragma unroll
    for (int c = 0; c < 8; c++) {
      int co = c * 32 + quad * 8;
      s16x8 xh0 = *(const s16x8*)&X[lq * 264 + co];
      s16x8 xl0 = *(const s16x8*)&X[8448 + lq * 264 + co];
      s16x8 xh1 = *(const s16x8*)&X[(16 + lq) * 264 + co];
      s16x8 xl1 = *(const s16x8*)&X[8448 + (16 + lq) * 264 + co];
#pragma unroll
      for (int mt = 0; mt < 4; mt++) {
        int aoff = (wv * 64 + mt * 16 + lq) * 256 + co;
        s16x8 wh = *(const s16x8*)(WhT + aoff);
        s16x8 wl = *(const s16x8*)(WlT + aoff);
        acc[mt][0] = MFMA16(wh, xh0, acc[mt][0]);
        acc[mt][0] = MFMA16(wl, xh0, acc[mt][0]);
        acc[mt][0] = MFMA16(wh, xl0, acc[mt][0]);
        acc[mt][1] = MFMA16(wh, xh1, acc[mt][1]);
        acc[mt][1] = MFMA16(wl, xh1, acc[mt][1]);
        acc[mt][1] = MFMA16(wh, xl1, acc[mt][1]);
      }
    }
    // V: fragment-major + swizzle. s = tl0 + nt*16 + lq
    _Float16* Vg = (_Float16*)Vt;
    int vb0 = bidx * 2097152 + (tl0 >> 6) * 16384 + ((tl0 >> 5) & 1) * 1024 +
              ((lq >> 3) & 1) * 8 + (lq & 7);
#pragma unroll
    for (int mt = 0; mt < 4; mt++) {
#pragma unroll
      for (int r = 0; r < 4; r++) {
        int drow = wv * 64 + mt * 16 + quad * 4 + r;
        float bb = bv[drow];
        int vc = (vb0 + (drow >> 5) * 2048 + (drow & 31) * 16) ^ swz8;
#pragma unroll
        for (int nt = 0; nt < 2; nt++) {
          Vg[vc + nt * 512] = (_Float16)(acc[mt][nt][r] + bb);
        }
      }
    }
  }
}

// ---------------- kernel 3: flash attention (fp16, q-block 128, 32x32) ------
// 256 blocks = 128 q-tiles x 2 s-blocks. 8 waves = 4 strips (32 q) x 2 shalf.
// vs R3: K/V global layout carries the bit6->bit3 XOR swizzle, so the
// ds_read_b128 8-lane groups tile all 32 banks (R3: 2-way conflict, 16.8M).
// Read side applies the same involution: h8 ^ ((lq32&4)<<1), a per-lane const.
__global__ __launch_bounds__(512, 2)
void attn_kernel(const short* __restrict__ Qf, const short* __restrict__ Kf,
                 const short* __restrict__ Vt,
                 float* __restrict__ out, float* __restrict__ O1,
                 float* __restrict__ Mlg) {
  __shared__ short sm[65536];          // 131072 B: buf{0,1} x [K 32KB | V 32KB]
  int tid = threadIdx.x;
  int lane = tid & 63, wv = tid >> 6;
  int lq32 = lane & 31, hh = lane >> 5, h8 = hh * 8;
  int h8s = h8 ^ ((lq32 & 4) << 1);    // swizzled fragment byte-slot
  int strip = wv & 3, sh = wv >> 2;
  int blk = blockIdx.x;
  int qt = blk >> 1, sblk = blk & 1;
  int row0g = qt * 128;
  int b = row0g >> 13;

  // Q fragments (B-operand): q = strip*32 + lq32, k = st*16 + h8 + j
  f16x8 qf[16];
  {
    const _Float16* qrow =
        (const _Float16*)Qf + (size_t)(row0g + strip * 32 + lq32) * 256 + h8;
#pragma unroll
    for (int st = 0; st < 16; st++) qf[st] = *(const f16x8*)(qrow + st * 16);
  }
  float m_ = -__builtin_inff();        // per-lane q
  float l_ = 0.f;
  f32x16 Oacc[8];                      // O^T[d = dt*32 + row][q]
#pragma unroll
  for (int dt = 0; dt < 8; dt++)
#pragma unroll
    for (int i = 0; i < 16; i++) Oacc[dt][i] = 0.f;

  // glds bases: per tile 32768 B; wave wv covers chunks wv*4..wv*4+3 (K and V)
  const char* gK = (const char*)Kf +
                   ((size_t)(b * 128 + sblk * 64) * 32768) + wv * 4096 + lane * 16;
  const char* gV = (const char*)Vt + (size_t)b * 4194304 +
                   (size_t)sblk * 2097152 + wv * 4096 + lane * 16;
  char* lds0 = (char*)sm;

  // issue tile 0 -> buf0
#pragma unroll
  for (int i = 0; i < 4; i++) {
    glds16(gK + i * 1024, lds0 + wv * 4096 + i * 1024);
    glds16(gV + i * 1024, lds0 + 32768 + wv * 4096 + i * 1024);
  }
  gK += 32768;
  gV += 32768;

  for (int it = 0; it < 64; it++) {
    int cub = it & 1;
    __syncthreads();                   // drains tile-it glds (vmcnt) + barrier
    if (it < 63) {                     // issue tile it+1 -> back buffer
      char* lb = lds0 + (cub ^ 1) * 65536;
#pragma unroll
      for (int i = 0; i < 4; i++) {
        glds16(gK + i * 1024, lb + wv * 4096 + i * 1024);
        glds16(gV + i * 1024, lb + 32768 + wv * 4096 + i * 1024);
      }
      gK += 32768;
      gV += 32768;
    }

    // S^T = K Q^T over wave's 32 s x 32 q (single-term fp16)
    f32x16 sacc;
#pragma unroll
    for (int i = 0; i < 16; i++) sacc[i] = 0.f;
    const short* KL = sm + cub * 32768 + sh * 512;
    __builtin_amdgcn_s_setprio(1);
#pragma unroll
    for (int st = 0; st < 16; st++) {
      f16x8 kf = *(const f16x8*)&KL[st * 1024 + lq32 * 16 + h8s];
      sacc = MFMA32H(kf, qf[st], sacc);
    }
    __builtin_amdgcn_s_setprio(0);

    // online softmax: max3-friendly tree + defer-max (THR=8)
    float a0 = fmaxf(fmaxf(sacc[0], sacc[1]), sacc[2]);
    float a1 = fmaxf(fmaxf(sacc[3], sacc[4]), sacc[5]);
    float a2 = fmaxf(fmaxf(sacc[6], sacc[7]), sacc[8]);
    float a3 = fmaxf(fmaxf(sacc[9], sacc[10]), sacc[11]);
    float a4 = fmaxf(fmaxf(sacc[12], sacc[13]), sacc[14]);
    float b0 = fmaxf(fmaxf(a0, a1), a2);
    float b1 = fmaxf(fmaxf(a3, a4), sacc[15]);
    float mx = fmaxf(b0, b1);
    mx = fmaxf(mx, __shfl_xor(mx, 32));
    if (__any(mx > m_ + 8.f)) {        // rescale only on real growth
      float mn = fmaxf(m_, mx);
      float alpha = __expf(m_ - mn);
      m_ = mn;
      l_ *= alpha;
#pragma unroll
      for (int dt = 0; dt < 8; dt++) Oacc[dt] = Oacc[dt] * alpha;
    }
    float rs = 0.f;
#pragma unroll
    for (int i = 0; i < 16; i++) {
      sacc[i] = __expf(sacc[i] - m_);
      rs += sacc[i];
    }
    rs += __shfl_xor(rs, 32);
    l_ += rs;

    // P -> PV B-fragments fully in registers.
    // Lane (q=lq32, hh) holds s = (r&3) + 8*(r>>2) + 4*hh for r=0..15.
    unsigned pa0 = pk16(sacc[0], sacc[1]), pa1 = pk16(sacc[2], sacc[3]);
    unsigned pb0 = pk16(sacc[4], sacc[5]), pb1 = pk16(sacc[6], sacc[7]);
    unsigned pc0 = pk16(sacc[8], sacc[9]), pc1 = pk16(sacc[10], sacc[11]);
    unsigned pd0 = pk16(sacc[12], sacc[13]), pd1 = pk16(sacc[14], sacc[15]);
    unsigned q0 = (unsigned)__shfl_xor((int)(hh ? pa0 : pb0), 32);
    unsigned q1 = (unsigned)__shfl_xor((int)(hh ? pa1 : pb1), 32);
    unsigned q2 = (unsigned)__shfl_xor((int)(hh ? pc0 : pd0), 32);
    unsigned q3 = (unsigned)__shfl_xor((int)(hh ? pc1 : pd1), 32);
    u32x4 P0 = hh ? (u32x4){q0, q1, pb0, pb1} : (u32x4){pa0, pa1, q0, q1};
    u32x4 P1 = hh ? (u32x4){q2, q3, pd0, pd1} : (u32x4){pc0, pc1, q2, q3};
    f16x8 pf0 = __builtin_bit_cast(f16x8, P0);
    f16x8 pf1 = __builtin_bit_cast(f16x8, P1);

    // O^T += V P^T (A = V rows from LDS, B = P in registers)
    const short* VL = sm + cub * 32768 + 16384 + sh * 1024;
    __builtin_amdgcn_s_setprio(1);
#pragma unroll
    for (int dt = 0; dt < 8; dt++) {
      f16x8 vf0 = *(const f16x8*)&VL[dt * 2048 + lq32 * 16 + h8s];
      f16x8 vf1 = *(const f16x8*)&VL[dt * 2048 + 512 + lq32 * 16 + h8s];
      Oacc[dt] = MFMA32H(vf0, pf0, Oacc[dt]);
      Oacc[dt] = MFMA32H(vf1, pf1, Oacc[dt]);
    }
    __builtin_amdgcn_s_setprio(0);
  }
  __syncthreads();                     // all loop readers done before smf reuse

  // ---- epilogue: shalf pair-merge + coalesced partial write ----
  float* smf = (float*)sm;             // Ob: 4 strips x [32 q][132] f32
  float* Msh = smf + 16896;            // m [2][4][32], l at +256
  if (lane < 32) {
    Msh[(sh * 4 + strip) * 32 + lq32] = m_;
    Msh[256 + (sh * 4 + strip) * 32 + lq32] = l_;
  }
  __syncthreads();
  float m1 = Msh[((1 - sh) * 4 + strip) * 32 + lq32];
  float l1 = Msh[256 + ((1 - sh) * 4 + strip) * 32 + lq32];
  float mm = fmaxf(m_, m1);
  float e0 = __expf(m_ - mm);
  float e1 = __expf(m1 - mm);
  float* Opart = (sblk == 0) ? out : O1;
  if (sh == 0 && lane < 32) {          // combined (m, l) for this s-block
    float lsum = l_ * e0 + l1 * e1;
    int rowq = row0g + strip * 32 + lq32;
    Mlg[sblk * 32768 + rowq * 2] = mm;
    Mlg[sblk * 32768 + rowq * 2 + 1] = lsum;
  }
  float* Ob = smf + strip * 4224;      // 32*132
#pragma unroll
  for (int hd = 0; hd < 2; hd++) {
    __syncthreads();
    if (sh == 1) {
#pragma unroll
      for (int dt2 = 0; dt2 < 4; dt2++) {
        int dt = hd * 4 + dt2;
#pragma unroll
        for (int g = 0; g < 4; g++) {
          f32x4 v = {Oacc[dt][g * 4], Oacc[dt][g * 4 + 1],
                     Oacc[dt][g * 4 + 2], Oacc[dt][g * 4 + 3]};
          *(f32x4*)&Ob[lq32 * 132 + dt2 * 32 + 8 * g + 4 * hh] = v;
        }
      }
    }
    __syncthreads();
    if (sh == 0) {
#pragma unroll
      for (int dt2 = 0; dt2 < 4; dt2++) {
        int dt = hd * 4 + dt2;
#pragma unroll
        for (int g = 0; g < 4; g++) {
          float* ad = &Ob[lq32 * 132 + dt2 * 32 + 8 * g + 4 * hh];
          f32x4 o1 = *(f32x4*)ad;
          f32x4 cmb;
#pragma unroll
          for (int j = 0; j < 4; j++)
            cmb[j] = Oacc[dt][g * 4 + j] * e0 + o1[j] * e1;
          *(f32x4*)ad = cmb;
        }
      }
    }
    __syncthreads();
    // cooperative coalesced write of this d-half: 128 q x 32 f32x4 groups
#pragma unroll
    for (int i = 0; i < 8; i++) {
      int idx = i * 512 + tid;
      int q = idx >> 5, gb = idx & 31;
      f32x4 v = *(f32x4*)&smf[(q >> 5) * 4224 + (q & 31) * 132 + gb * 4];
      *(f32x4*)&Opart[(size_t)(row0g + q) * 256 + hd * 128 + gb * 4] = v;
    }
  }
}

// ---------------- kernel 4: s-split merge ----------------
__global__ void merge_kernel(const float* __restrict__ O1,
                             const float* __restrict__ Mlg,
                             float* __restrict__ out) {
  int idx = blockIdx.x * 256 + threadIdx.x;   // 4096 blocks
  int q = idx >> 6, dg = idx & 63;
  float m0 = Mlg[q * 2], l0 = Mlg[q * 2 + 1];
  float m1 = Mlg[32768 + q * 2], l1 = Mlg[32768 + q * 2 + 1];
  float mm = fmaxf(m0, m1);
  float e0 = __expf(m0 - mm), e1 = __expf(m1 - mm);
  float inv = 1.f / (l0 * e0 + l1 * e1);
  f32x4 a = *(const f32x4*)(out + (size_t)q * 256 + dg * 4);
  f32x4 bb = *(const f32x4*)(O1 + (size_t)q * 256 + dg * 4);
  f32x4 r;
#pragma unroll
  for (int j = 0; j < 4; j++) r[j] = (a[j] * e0 + bb[j] * e1) * inv;
  *(f32x4*)(out + (size_t)q * 256 + dg * 4) = r;
}

// ---------------- launcher ----------------
extern "C" void kernel_launch(void* const* d_in, const int* in_sizes, int n_in,
                              void* d_out, int out_size, void* d_ws, size_t ws_size,
                              hipStream_t stream) {
  const float* x  = (const float*)d_in[0];
  const float* Wq = (const float*)d_in[1];
  const float* bq = (const float*)d_in[2];
  const float* Wk = (const float*)d_in[3];
  const float* bk = (const float*)d_in[4];
  const float* Wv = (const float*)d_in[5];
  const float* bv = (const float*)d_in[6];
  float* out = (float*)d_out;
  short* ws = (short*)d_ws;
  // ws layout (shorts): wt 393216 | Qf 4194304 | Kf 4194304 | Vt 4194304 |
  // O1 (float 4194304) at short-offset 12976128. Mlg aliases wt (dead after
  // qkv). Total = 42,729,472 B.
  short* wt = ws;
  short* Qf = ws + 393216;
  short* Kf = Qf + 4194304;
  short* Vt = Kf + 4194304;
  float* O1  = (float*)(ws + 12976128);
  float* Mlg = (float*)ws;
  hipLaunchKernelGGL(wtrans_kernel, dim3(768), dim3(256), 0, stream, Wq, Wk, Wv, wt);
  hipLaunchKernelGGL(qkv_kernel, dim3(512), dim3(256), 0, stream,
                     x, bq, bk, bv, wt, Qf, Kf, Vt);
  hipLaunchKernelGGL(attn_kernel, dim3(256), dim3(512), 0, stream,
                     Qf, Kf, Vt, out, O1, Mlg);
  hipLaunchKernelGGL(merge_kernel, dim3(4096), dim3(256), 0, stream,
                     O1, Mlg, out);
}

// Round 5
// 262.129 us; speedup vs baseline: 1.4774x; 1.1487x over previous
//
#include <hip/hip_runtime.h>
#include <stdint.h>

// ---- types ----
typedef __attribute__((ext_vector_type(4))) float f32x4;
typedef __attribute__((ext_vector_type(16))) float f32x16;
typedef __attribute__((ext_vector_type(8))) short s16x8;
typedef __attribute__((ext_vector_type(4))) short s16x4;
typedef __attribute__((ext_vector_type(4))) unsigned int u32x4;
typedef __attribute__((ext_vector_type(8))) _Float16 f16x8;
typedef __attribute__((ext_vector_type(4))) _Float16 f16x4;
typedef __attribute__((ext_vector_type(2))) _Float16 f16x2;

#define MFMA16(a, b, c) __builtin_amdgcn_mfma_f32_16x16x32_bf16((a), (b), (c), 0, 0, 0)
#define MFMA32H(a, b, c) __builtin_amdgcn_mfma_f32_32x32x16_f16((a), (b), (c), 0, 0, 0)

// B=2, T=8192, D=256; rows = B*T = 16384 flat.

__device__ __forceinline__ unsigned short f2bf(float f) {
  unsigned int u = __float_as_uint(f);
  u += 0x7FFFu + ((u >> 16) & 1u);  // RNE
  return (unsigned short)(u >> 16);
}
__device__ __forceinline__ float bf2f(unsigned short h) {
  return __uint_as_float(((unsigned int)h) << 16);
}
__device__ __forceinline__ unsigned pk16(float a, float b) {
  f16x2 p;
  p[0] = (_Float16)a;  // RNE
  p[1] = (_Float16)b;
  return __builtin_bit_cast(unsigned, p);
}

// async global->LDS, 16 B per lane; gptr per-lane, lptr wave-uniform base.
typedef const __attribute__((address_space(1))) void gas_void;
typedef __attribute__((address_space(3))) void las_void;
__device__ __forceinline__ void glds16(const void* g, void* l) {
  __builtin_amdgcn_global_load_lds((gas_void*)g, (las_void*)l, 16, 0, 0);
}

// ---------------- kernel 1: weight transpose + hi/lo split (bf16) -----------
__global__ void wtrans_kernel(const float* __restrict__ Wq,
                              const float* __restrict__ Wk,
                              const float* __restrict__ Wv,
                              short* __restrict__ wt) {
  int idx = blockIdx.x * 256 + threadIdx.x;   // 768 blocks * 256
  int w = idx >> 16;
  int rc = idx & 65535;
  int d = rc >> 8;
  int n = rc & 255;
  const float* Ws = (w == 0) ? Wq : ((w == 1) ? Wk : Wv);
  float v = Ws[rc];
  unsigned short hi = f2bf(v);
  unsigned short lo = f2bf(v - bf2f(hi));
  short* th = wt + w * 131072;
  th[n * 256 + d] = (short)hi;
  th[65536 + n * 256 + d] = (short)lo;
}

// ---------------- kernel 2: QKV projection (3-term bf16 MFMA) ----------------
// REWRITE vs R4: 256 blocks x 512 thr, 64 rows/block; X hi/lo staged once in
// LDS; each wave owns a 64-col output strip (Q: wv 0-3, K: wv 4-7) then a
// 32-d V strip. Per c-step a wave loads 8 weight fragments and reuses each
// across 4 row-tiles (load:MFMA 1:6 vs old 1:1.5; weight traffic/block =
// exactly one 768 KB set, L2-resident). Output layouts BIT-IDENTICAL to R4:
// Qf [16384][256] row-major fp16;
// Kf frag idx = (row>>6)*16384 + (col>>4)*1024 + ((row>>5)&1)*512
//   + (row&31)*16 + ((col>>3)&1)*8 + (col&7), ^ ((idx>>6)&1)<<3 [= (quad&1)<<3]
// Vt frag idx = b*2097152 + (s>>6)*16384 + (d>>5)*2048 + ((s>>5)&1)*1024
//   + ((s>>4)&1)*512 + (d&31)*16 + ((s>>3)&1)*8 + (s&7), ^ same bit.
__global__ __launch_bounds__(512, 2)
void qkv_kernel(const float* __restrict__ x,
                const float* __restrict__ bq,
                const float* __restrict__ bk,
                const float* __restrict__ bv,
                const short* __restrict__ wt,
                short* __restrict__ Qf, short* __restrict__ Kf,
                short* __restrict__ Vt) {
  __shared__ short X[33792];           // hi [64][264]; lo at +16896
  int tid = threadIdx.x;
  int blk = blockIdx.x;
  int r0 = blk * 64;
  int b = r0 >> 13;
  int tl0 = r0 & 8191;
#pragma unroll
  for (int i = 0; i < 8; i++) {
    int E = i * 2048 + tid * 4;
    int r = E >> 8, col = E & 255;
    f32x4 v = *(const f32x4*)(x + (size_t)(r0 + r) * 256 + col);
    s16x4 h, lo;
#pragma unroll
    for (int j = 0; j < 4; j++) {
      unsigned short hh = f2bf(v[j]);
      h[j] = (short)hh;
      lo[j] = (short)f2bf(v[j] - bf2f(hh));
    }
    *(s16x4*)&X[r * 264 + col] = h;
    *(s16x4*)&X[16896 + r * 264 + col] = lo;
  }
  __syncthreads();

  int lane = tid & 63, wv = tid >> 6;
  int quad = lane >> 4, lq = lane & 15;
  int swz8 = (quad & 1) << 3;          // bank-swizzle bit (bit6->bit3)

  // ---- Q/K: wave wv<4 -> Q col-strip wv; wv>=4 -> K col-strip wv-4 ----
  {
    int strip = wv & 3;
    bool isK = wv >= 4;
    const short* WhT = wt + (isK ? 131072 : 0);
    const short* WlT = WhT + 65536;
    f32x4 acc[4][4];
#pragma unroll
    for (int mt = 0; mt < 4; mt++)
#pragma unroll
      for (int nt = 0; nt < 4; nt++) acc[mt][nt] = (f32x4){0.f, 0.f, 0.f, 0.f};
#pragma unroll
    for (int c = 0; c < 8; c++) {
      int co = c * 32 + quad * 8;
      s16x8 wh[4], wl[4];
#pragma unroll
      for (int nt = 0; nt < 4; nt++) {
        int boff = (strip * 64 + nt * 16 + lq) * 256 + co;
        wh[nt] = *(const s16x8*)(WhT + boff);
        wl[nt] = *(const s16x8*)(WlT + boff);
      }
#pragma unroll
      for (int mt = 0; mt < 4; mt++) {
        s16x8 xh = *(const s16x8*)&X[(mt * 16 + lq) * 264 + co];
        s16x8 xl = *(const s16x8*)&X[16896 + (mt * 16 + lq) * 264 + co];
#pragma unroll
        for (int nt = 0; nt < 4; nt++) {
          acc[mt][nt] = MFMA16(xh, wh[nt], acc[mt][nt]);
          acc[mt][nt] = MFMA16(xl, wh[nt], acc[mt][nt]);
          acc[mt][nt] = MFMA16(xh, wl[nt], acc[mt][nt]);
        }
      }
    }
    const float* bias = isK ? bk : bq;
    if (!isK) {                        // Q: row-major fp16
      _Float16* Of = (_Float16*)Qf;
#pragma unroll
      for (int nt = 0; nt < 4; nt++) {
        int col = strip * 64 + nt * 16 + lq;
        float bb = bias[col];
#pragma unroll
        for (int mt = 0; mt < 4; mt++)
#pragma unroll
          for (int r = 0; r < 4; r++) {
            int row = r0 + mt * 16 + quad * 4 + r;
            Of[row * 256 + col] = (_Float16)(acc[mt][nt][r] + bb);
          }
      }
    } else {                           // K: fragment-major + swizzle
      _Float16* Of = (_Float16*)Kf;
      int kb0 = blk * 16384;           // rows r0..r0+63 share row>>6 = blk
#pragma unroll
      for (int nt = 0; nt < 4; nt++) {
        int col = strip * 64 + nt * 16 + lq;
        float bb = bias[col];
        int colpart = (col >> 4) * 1024 + ((col >> 3) & 1) * 8 + (col & 7);
#pragma unroll
        for (int mt = 0; mt < 4; mt++)
#pragma unroll
          for (int r = 0; r < 4; r++) {
            int srow = mt * 16 + quad * 4 + r;
            int idx = (kb0 + ((srow >> 5) & 1) * 512 + colpart +
                       (srow & 31) * 16) ^ swz8;
            Of[idx] = (_Float16)(acc[mt][nt][r] + bb);
          }
      }
    }
  }

  // ---- V: wave wv owns d-rows 32wv..32wv+31, all 64 s ----
  {
    const short* VhT = wt + 262144;
    const short* VlT = wt + 327680;
    f32x4 av[2][4];
#pragma unroll
    for (int sub = 0; sub < 2; sub++)
#pragma unroll
      for (int st = 0; st < 4; st++) av[sub][st] = (f32x4){0.f, 0.f, 0.f, 0.f};
#pragma unroll
    for (int c = 0; c < 8; c++) {
      int co = c * 32 + quad * 8;
      s16x8 vh[2], vl[2];
#pragma unroll
      for (int sub = 0; sub < 2; sub++) {
        int aoff = (wv * 32 + sub * 16 + lq) * 256 + co;
        vh[sub] = *(const s16x8*)(VhT + aoff);
        vl[sub] = *(const s16x8*)(VlT + aoff);
      }
#pragma unroll
      for (int st = 0; st < 4; st++) {
        s16x8 xh = *(const s16x8*)&X[(st * 16 + lq) * 264 + co];
        s16x8 xl = *(const s16x8*)&X[16896 + (st * 16 + lq) * 264 + co];
#pragma unroll
        for (int sub = 0; sub < 2; sub++) {
          av[sub][st] = MFMA16(vh[sub], xh, av[sub][st]);
          av[sub][st] = MFMA16(vl[sub], xh, av[sub][st]);
          av[sub][st] = MFMA16(vh[sub], xl, av[sub][st]);
        }
      }
    }
    _Float16* Vg = (_Float16*)Vt;
    int vbase = b * 2097152 + (tl0 >> 6) * 16384 + wv * 2048 +
                ((lq >> 3) & 1) * 8 + (lq & 7);
#pragma unroll
    for (int sub = 0; sub < 2; sub++)
#pragma unroll
      for (int r = 0; r < 4; r++) {
        int d31 = sub * 16 + quad * 4 + r;
        float bb = bv[wv * 32 + d31];
#pragma unroll
        for (int st = 0; st < 4; st++) {
          int idx = (vbase + ((st >> 1) & 1) * 1024 + (st & 1) * 512 +
                     d31 * 16) ^ swz8;
          Vg[idx] = (_Float16)(av[sub][st][r] + bb);
        }
      }
  }
}

// ---------------- kernel 3: flash attention (fp16, q-block 128, 32x32) ------
// UNCHANGED from R4 (known-good, 171 us). 256 blocks = 128 q-tiles x 2
// s-blocks; 8 waves = 4 strips x 2 shalf; K/V via glds from fragment-major
// global; P in registers; defer-max THR=8. Note: the 16.78M
// SQ_LDS_BANK_CONFLICT is structural to glds LDS-writes (R3==R4 exactly),
// not ds_reads — do not chase it.
__global__ __launch_bounds__(512, 2)
void attn_kernel(const short* __restrict__ Qf, const short* __restrict__ Kf,
                 const short* __restrict__ Vt,
                 float* __restrict__ out, float* __restrict__ O1,
                 float* __restrict__ Mlg) {
  __shared__ short sm[65536];          // 131072 B: buf{0,1} x [K 32KB | V 32KB]
  int tid = threadIdx.x;
  int lane = tid & 63, wv = tid >> 6;
  int lq32 = lane & 31, hh = lane >> 5, h8 = hh * 8;
  int h8s = h8 ^ ((lq32 & 4) << 1);    // swizzled fragment byte-slot
  int strip = wv & 3, sh = wv >> 2;
  int blk = blockIdx.x;
  int qt = blk >> 1, sblk = blk & 1;
  int row0g = qt * 128;
  int b = row0g >> 13;

  // Q fragments (B-operand): q = strip*32 + lq32, k = st*16 + h8 + j
  f16x8 qf[16];
  {
    const _Float16* qrow =
        (const _Float16*)Qf + (size_t)(row0g + strip * 32 + lq32) * 256 + h8;
#pragma unroll
    for (int st = 0; st < 16; st++) qf[st] = *(const f16x8*)(qrow + st * 16);
  }
  float m_ = -__builtin_inff();        // per-lane q
  float l_ = 0.f;
  f32x16 Oacc[8];                      // O^T[d = dt*32 + row][q]
#pragma unroll
  for (int dt = 0; dt < 8; dt++)
#pragma unroll
    for (int i = 0; i < 16; i++) Oacc[dt][i] = 0.f;

  // glds bases: per tile 32768 B; wave wv covers chunks wv*4..wv*4+3 (K and V)
  const char* gK = (const char*)Kf +
                   ((size_t)(b * 128 + sblk * 64) * 32768) + wv * 4096 + lane * 16;
  const char* gV = (const char*)Vt + (size_t)b * 4194304 +
                   (size_t)sblk * 2097152 + wv * 4096 + lane * 16;
  char* lds0 = (char*)sm;

  // issue tile 0 -> buf0
#pragma unroll
  for (int i = 0; i < 4; i++) {
    glds16(gK + i * 1024, lds0 + wv * 4096 + i * 1024);
    glds16(gV + i * 1024, lds0 + 32768 + wv * 4096 + i * 1024);
  }
  gK += 32768;
  gV += 32768;

  for (int it = 0; it < 64; it++) {
    int cub = it & 1;
    __syncthreads();                   // drains tile-it glds (vmcnt) + barrier
    if (it < 63) {                     // issue tile it+1 -> back buffer
      char* lb = lds0 + (cub ^ 1) * 65536;
#pragma unroll
      for (int i = 0; i < 4; i++) {
        glds16(gK + i * 1024, lb + wv * 4096 + i * 1024);
        glds16(gV + i * 1024, lb + 32768 + wv * 4096 + i * 1024);
      }
      gK += 32768;
      gV += 32768;
    }

    // S^T = K Q^T over wave's 32 s x 32 q (single-term fp16)
    f32x16 sacc;
#pragma unroll
    for (int i = 0; i < 16; i++) sacc[i] = 0.f;
    const short* KL = sm + cub * 32768 + sh * 512;
    __builtin_amdgcn_s_setprio(1);
#pragma unroll
    for (int st = 0; st < 16; st++) {
      f16x8 kf = *(const f16x8*)&KL[st * 1024 + lq32 * 16 + h8s];
      sacc = MFMA32H(kf, qf[st], sacc);
    }
    __builtin_amdgcn_s_setprio(0);

    // online softmax: max3-friendly tree + defer-max (THR=8)
    float a0 = fmaxf(fmaxf(sacc[0], sacc[1]), sacc[2]);
    float a1 = fmaxf(fmaxf(sacc[3], sacc[4]), sacc[5]);
    float a2 = fmaxf(fmaxf(sacc[6], sacc[7]), sacc[8]);
    float a3 = fmaxf(fmaxf(sacc[9], sacc[10]), sacc[11]);
    float a4 = fmaxf(fmaxf(sacc[12], sacc[13]), sacc[14]);
    float b0 = fmaxf(fmaxf(a0, a1), a2);
    float b1 = fmaxf(fmaxf(a3, a4), sacc[15]);
    float mx = fmaxf(b0, b1);
    mx = fmaxf(mx, __shfl_xor(mx, 32));
    if (__any(mx > m_ + 8.f)) {        // rescale only on real growth
      float mn = fmaxf(m_, mx);
      float alpha = __expf(m_ - mn);
      m_ = mn;
      l_ *= alpha;
#pragma unroll
      for (int dt = 0; dt < 8; dt++) Oacc[dt] = Oacc[dt] * alpha;
    }
    float rs = 0.f;
#pragma unroll
    for (int i = 0; i < 16; i++) {
      sacc[i] = __expf(sacc[i] - m_);
      rs += sacc[i];
    }
    rs += __shfl_xor(rs, 32);
    l_ += rs;

    // P -> PV B-fragments fully in registers.
    // Lane (q=lq32, hh) holds s = (r&3) + 8*(r>>2) + 4*hh for r=0..15.
    unsigned pa0 = pk16(sacc[0], sacc[1]), pa1 = pk16(sacc[2], sacc[3]);
    unsigned pb0 = pk16(sacc[4], sacc[5]), pb1 = pk16(sacc[6], sacc[7]);
    unsigned pc0 = pk16(sacc[8], sacc[9]), pc1 = pk16(sacc[10], sacc[11]);
    unsigned pd0 = pk16(sacc[12], sacc[13]), pd1 = pk16(sacc[14], sacc[15]);
    unsigned q0 = (unsigned)__shfl_xor((int)(hh ? pa0 : pb0), 32);
    unsigned q1 = (unsigned)__shfl_xor((int)(hh ? pa1 : pb1), 32);
    unsigned q2 = (unsigned)__shfl_xor((int)(hh ? pc0 : pd0), 32);
    unsigned q3 = (unsigned)__shfl_xor((int)(hh ? pc1 : pd1), 32);
    u32x4 P0 = hh ? (u32x4){q0, q1, pb0, pb1} : (u32x4){pa0, pa1, q0, q1};
    u32x4 P1 = hh ? (u32x4){q2, q3, pd0, pd1} : (u32x4){pc0, pc1, q2, q3};
    f16x8 pf0 = __builtin_bit_cast(f16x8, P0);
    f16x8 pf1 = __builtin_bit_cast(f16x8, P1);

    // O^T += V P^T (A = V rows from LDS, B = P in registers)
    const short* VL = sm + cub * 32768 + 16384 + sh * 1024;
    __builtin_amdgcn_s_setprio(1);
#pragma unroll
    for (int dt = 0; dt < 8; dt++) {
      f16x8 vf0 = *(const f16x8*)&VL[dt * 2048 + lq32 * 16 + h8s];
      f16x8 vf1 = *(const f16x8*)&VL[dt * 2048 + 512 + lq32 * 16 + h8s];
      Oacc[dt] = MFMA32H(vf0, pf0, Oacc[dt]);
      Oacc[dt] = MFMA32H(vf1, pf1, Oacc[dt]);
    }
    __builtin_amdgcn_s_setprio(0);
  }
  __syncthreads();                     // all loop readers done before smf reuse

  // ---- epilogue: shalf pair-merge + coalesced partial write ----
  float* smf = (float*)sm;             // Ob: 4 strips x [32 q][132] f32
  float* Msh = smf + 16896;            // m [2][4][32], l at +256
  if (lane < 32) {
    Msh[(sh * 4 + strip) * 32 + lq32] = m_;
    Msh[256 + (sh * 4 + strip) * 32 + lq32] = l_;
  }
  __syncthreads();
  float m1 = Msh[((1 - sh) * 4 + strip) * 32 + lq32];
  float l1 = Msh[256 + ((1 - sh) * 4 + strip) * 32 + lq32];
  float mm = fmaxf(m_, m1);
  float e0 = __expf(m_ - mm);
  float e1 = __expf(m1 - mm);
  float* Opart = (sblk == 0) ? out : O1;
  if (sh == 0 && lane < 32) {          // combined (m, l) for this s-block
    float lsum = l_ * e0 + l1 * e1;
    int rowq = row0g + strip * 32 + lq32;
    Mlg[sblk * 32768 + rowq * 2] = mm;
    Mlg[sblk * 32768 + rowq * 2 + 1] = lsum;
  }
  float* Ob = smf + strip * 4224;      // 32*132
#pragma unroll
  for (int hd = 0; hd < 2; hd++) {
    __syncthreads();
    if (sh == 1) {
#pragma unroll
      for (int dt2 = 0; dt2 < 4; dt2++) {
        int dt = hd * 4 + dt2;
#pragma unroll
        for (int g = 0; g < 4; g++) {
          f32x4 v = {Oacc[dt][g * 4], Oacc[dt][g * 4 + 1],
                     Oacc[dt][g * 4 + 2], Oacc[dt][g * 4 + 3]};
          *(f32x4*)&Ob[lq32 * 132 + dt2 * 32 + 8 * g + 4 * hh] = v;
        }
      }
    }
    __syncthreads();
    if (sh == 0) {
#pragma unroll
      for (int dt2 = 0; dt2 < 4; dt2++) {
        int dt = hd * 4 + dt2;
#pragma unroll
        for (int g = 0; g < 4; g++) {
          float* ad = &Ob[lq32 * 132 + dt2 * 32 + 8 * g + 4 * hh];
          f32x4 o1 = *(f32x4*)ad;
          f32x4 cmb;
#pragma unroll
          for (int j = 0; j < 4; j++)
            cmb[j] = Oacc[dt][g * 4 + j] * e0 + o1[j] * e1;
          *(f32x4*)ad = cmb;
        }
      }
    }
    __syncthreads();
    // cooperative coalesced write of this d-half: 128 q x 32 f32x4 groups
#pragma unroll
    for (int i = 0; i < 8; i++) {
      int idx = i * 512 + tid;
      int q = idx >> 5, gb = idx & 31;
      f32x4 v = *(f32x4*)&smf[(q >> 5) * 4224 + (q & 31) * 132 + gb * 4];
      *(f32x4*)&Opart[(size_t)(row0g + q) * 256 + hd * 128 + gb * 4] = v;
    }
  }
}

// ---------------- kernel 4: s-split merge ----------------
__global__ void merge_kernel(const float* __restrict__ O1,
                             const float* __restrict__ Mlg,
                             float* __restrict__ out) {
  int idx = blockIdx.x * 256 + threadIdx.x;   // 4096 blocks
  int q = idx >> 6, dg = idx & 63;
  float m0 = Mlg[q * 2], l0 = Mlg[q * 2 + 1];
  float m1 = Mlg[32768 + q * 2], l1 = Mlg[32768 + q * 2 + 1];
  float mm = fmaxf(m0, m1);
  float e0 = __expf(m0 - mm), e1 = __expf(m1 - mm);
  float inv = 1.f / (l0 * e0 + l1 * e1);
  f32x4 a = *(const f32x4*)(out + (size_t)q * 256 + dg * 4);
  f32x4 bb = *(const f32x4*)(O1 + (size_t)q * 256 + dg * 4);
  f32x4 r;
#pragma unroll
  for (int j = 0; j < 4; j++) r[j] = (a[j] * e0 + bb[j] * e1) * inv;
  *(f32x4*)(out + (size_t)q * 256 + dg * 4) = r;
}

// ---------------- launcher ----------------
extern "C" void kernel_launch(void* const* d_in, const int* in_sizes, int n_in,
                              void* d_out, int out_size, void* d_ws, size_t ws_size,
                              hipStream_t stream) {
  const float* x  = (const float*)d_in[0];
  const float* Wq = (const float*)d_in[1];
  const float* bq = (const float*)d_in[2];
  const float* Wk = (const float*)d_in[3];
  const float* bk = (const float*)d_in[4];
  const float* Wv = (const float*)d_in[5];
  const float* bv = (const float*)d_in[6];
  float* out = (float*)d_out;
  short* ws = (short*)d_ws;
  // ws layout (shorts): wt 393216 | Qf 4194304 | Kf 4194304 | Vt 4194304 |
  // O1 (float 4194304) at short-offset 12976128. Mlg aliases wt (dead after
  // qkv). Total = 42,729,472 B.
  short* wt = ws;
  short* Qf = ws + 393216;
  short* Kf = Qf + 4194304;
  short* Vt = Kf + 4194304;
  float* O1  = (float*)(ws + 12976128);
  float* Mlg = (float*)ws;
  hipLaunchKernelGGL(wtrans_kernel, dim3(768), dim3(256), 0, stream, Wq, Wk, Wv, wt);
  hipLaunchKernelGGL(qkv_kernel, dim3(256), dim3(512), 0, stream,
                     x, bq, bk, bv, wt, Qf, Kf, Vt);
  hipLaunchKernelGGL(attn_kernel, dim3(256), dim3(512), 0, stream,
                     Qf, Kf, Vt, out, O1, Mlg);
  hipLaunchKernelGGL(merge_kernel, dim3(4096), dim3(256), 0, stream,
                     O1, Mlg, out);
}